// Round 12
// baseline (116.259 us; speedup 1.0000x reference)
//
#include <hip/hip_runtime.h>

typedef unsigned int  u32;
typedef unsigned short u16;

typedef float    f4  __attribute__((ext_vector_type(4)));
typedef short    bf8 __attribute__((ext_vector_type(8)));
typedef __fp16   h8  __attribute__((ext_vector_type(8)));
typedef __fp16   h2  __attribute__((ext_vector_type(2)));

#define NBLK  2048
#define ITERS 2      // 2048 * 2 * 64 = 262144 boards; 8 blocks/CU resident (VGPR=64, LDS~20KB)
#define ZSTR  104    // z1 row stride (u16); 52 dw/row spreads b128 starts over all 8 bank slots

// round-to-nearest-even fp32 -> bf16 bits
__device__ __forceinline__ u32 bfr(float f) {
    union { float f; u32 u; } v; v.f = f;
    return (v.u + 0x7fffu + ((v.u >> 16) & 1u)) >> 16;
}
__device__ __forceinline__ u32 pk2(float lo, float hi) { return bfr(lo) | (bfr(hi) << 16); }
__device__ __forceinline__ u32 pkh(float lo, float hi) {   // fp16 pair (RTZ, 1 inst)
    union { h2 h; u32 u; } v; v.h = __builtin_amdgcn_cvt_pkrtz(lo, hi); return v.u;
}
__device__ __forceinline__ u32 nrev(u32 x) {
    return ((x >> 12) & 0xFu) | ((x >> 4) & 0xF0u) | ((x << 4) & 0xF00u) | ((x << 12) & 0xF000u);
}

__launch_bounds__(256, 4)
__global__ void smartcnn_fused(const int* __restrict__ exps,
                               const float* __restrict__ c0w, const float* __restrict__ c0b,
                               const float* __restrict__ c1w,
                               const float* __restrict__ lw,  const float* __restrict__ lb,
                               const float* __restrict__ ow,  const float* __restrict__ ob,
                               float* __restrict__ out)
{
    __shared__ uint2  ThA[121];         // [v1*11+v2] -> 4 channels bf16 (relu(conv0 pair + bias))
    __shared__ uint2  TvA[121];         // [v1*11+v2] -> 4 channels bf16 (relu(conv1 pair))
    __shared__ u16    z1[64 * ZSTR];    // [G*16+m][k] bf16, k = 4*pos + channel (permuted K)
    __shared__ float4 Pbuf[4][4][16];   // [G][wave][m] logit partials
    __shared__ u32    flg[64];          // flip flags per board

    const int tid  = threadIdx.x;
    const int w    = tid >> 6;
    const int lane = tid & 63;
    const int m    = lane & 15;
    const int qd   = lane >> 4;

    // Feature permutation across GEMM1 M-tiles: tile tt, tile-row i=4q+r holds
    // feature base(tt)+8q+r  (base = 0,4,32,36). Then lane (qd,m)'s accumulator
    // rows are exactly the GEMM2 B-frag features 32c+8qd+j -> no staging needed.
    // lw rows and lb follow this permutation; ow stays canonical.

    // ---- packed-channel pair tables ----
    for (int i = tid; i < 121; i += 256) {
        int v1 = i / 11, v2 = i - v1 * 11;
        float hv[4], vv[4];
        #pragma unroll
        for (int c = 0; c < 4; ++c) {
            hv[c] = fmaxf(c0w[c*24 + 0] + c0w[c*24 + (1+v1)*2 + 0] + c0b[c]
                        + c0w[c*24 + 1] + c0w[c*24 + (1+v2)*2 + 1], 0.f);
            vv[c] = fmaxf(c1w[c*24 + 0] + c1w[c*24 + (1+v1)*2 + 0]
                        + c1w[c*24 + 1] + c1w[c*24 + (1+v2)*2 + 1], 0.f);
        }
        ThA[i] = make_uint2(pk2(hv[0], hv[1]), pk2(hv[2], hv[3]));
        TvA[i] = make_uint2(pk2(vv[0], vv[1]), pk2(vv[2], vv[3]));
    }

    // ---- W1 A-fragments (48 VGPR), K-permuted, M-permuted, staged through z1 ----
    // FULLY UNROLLED over tt: af must be statically indexed or it demotes to scratch
    // (R8 post-mortem). Same-wave DS ops are in-order => WAR-safe reuse of z1 rows.
    bf8 af[4][3];
    {
        u16* srow = &z1[(w*16 + m) * ZSTR];
        #pragma unroll
        for (int tt = 0; tt < 4; ++tt) {
            const int tbase = ((tt & 1) ? 4 : 0) + ((tt >> 1) ? 32 : 0);
            const int fid = 64*w + tbase + 8*(m >> 2) + (m & 3);   // M-permuted feature row
            const float* rowp = lw + (size_t)fid*96 + qd*24;
            #pragma unroll
            for (int v = 0; v < 6; ++v) {
                float4 x = *(const float4*)(rowp + v*4);
                u16 e[4] = {(u16)bfr(x.x), (u16)bfr(x.y), (u16)bfr(x.z), (u16)bfr(x.w)};
                #pragma unroll
                for (int j = 0; j < 4; ++j) {
                    int ko = qd*24 + v*4 + j;
                    int kp = (ko < 48) ? ((ko % 12)*4 + ko/12)
                                       : (48 + ((ko - 48) % 12)*4 + (ko - 48)/12);
                    srow[kp] = e[j];
                }
            }
            #pragma unroll
            for (int s = 0; s < 3; ++s)
                af[tt][s] = *(const bf8*)(srow + s*32 + qd*8);
        }
    }
    // ---- out_w A-fragments, fp16 (8 VGPR): rows 0-3 = actions, rows 4-15 = 0 ----
    u32 owA[2][4];
    #pragma unroll
    for (int c = 0; c < 2; ++c) {
        int n8 = 64*w + 32*c + qd*8;
        #pragma unroll
        for (int k = 0; k < 4; ++k)
            owA[c][k] = (m < 4) ? pkh(ow[m*256 + n8 + 2*k], ow[m*256 + n8 + 2*k + 1]) : 0u;
    }
    // ---- linear_b as f4, M-permuted: lb4[tt][r] = lb[64w + tbase(tt) + 8qd + r] ----
    f4 lb4[4];
    #pragma unroll
    for (int tt = 0; tt < 4; ++tt) {
        const int tbase = ((tt & 1) ? 4 : 0) + ((tt >> 1) ? 32 : 0);
        lb4[tt] = *(const f4*)(lb + 64*w + tbase + 8*qd);
    }
    const float4 obv = *(const float4*)ob;

    const int b0 = blockIdx.x * (ITERS * 64);
    __syncthreads();  // tables + af staging done before z1 reuse

    int4 e4 = *(const int4*)(exps + (size_t)(b0 + w*16 + m)*16 + qd*4);
    u32 fl = 0;  // flip flags for the pending epilogue, carried in-register

    #pragma unroll 1
    for (int it = 0; it < ITERS; ++it) {
        // ---- epilogue for iteration it-1 (reads Pbuf written before last barrier) ----
        if (it > 0) {
            float4 s0 = Pbuf[qd][0][m], s1 = Pbuf[qd][1][m];
            float4 s2 = Pbuf[qd][2][m], s3 = Pbuf[qd][3][m];
            float L0 = s0.x + s1.x + s2.x + s3.x + obv.x;
            float L1 = s0.y + s1.y + s2.y + s3.y + obv.y;
            float L2 = s0.z + s1.z + s2.z + s3.z + obv.z;
            float L3 = s0.w + s1.w + s2.w + s3.w + obv.w;
            float mx = fmaxf(fmaxf(L0, L1), fmaxf(L2, L3));
            float e0 = __expf(L0 - mx), e1 = __expf(L1 - mx), e2 = __expf(L2 - mx), e3 = __expf(L3 - mx);
            float inv = 1.0f / (e0 + e1 + e2 + e3);
            float p0 = e0 * inv, p1 = e1 * inv, p2 = e2 * inv, p3 = e3 * inv;
            float4 o;
            o.x = (fl & 1u) ? p1 : p0;
            o.y = (fl & 1u) ? p0 : p1;
            o.z = (fl & 2u) ? p3 : p2;
            o.w = (fl & 2u) ? p2 : p3;
            *(float4*)(out + (size_t)(b0 + (it-1)*64 + qd*16 + m) * 4) = o;
        }

        // ---- phase 1: build z1 + flg for this iteration's 64 boards ----
        {
            u32 pkd = (u32)e4.x | ((u32)e4.y << 4) | ((u32)e4.z << 8) | ((u32)e4.w << 12);
            u32 R0 = (u32)__shfl((int)pkd, m);
            u32 R1 = (u32)__shfl((int)pkd, m + 16);
            u32 R2 = (u32)__shfl((int)pkd, m + 32);
            u32 R3 = (u32)__shfl((int)pkd, m + 48);
            u32 c0v = R0 & 15u, c1v = (R0 >> 12) & 15u, c2v = R3 & 15u, c3v = (R3 >> 12) & 15u;
            u32 best = c0v; int ix = 0;
            if (c1v > best) { best = c1v; ix = 1; }
            if (c2v > best) { best = c2v; ix = 2; }
            if (c3v > best) { best = c3v; ix = 3; }
            const bool fv = (ix >= 2), fh = ((ix & 1) != 0);
            u32 F[4];
            F[0] = fv ? R3 : R0;
            F[1] = fv ? R2 : R1;
            F[2] = fv ? R1 : R2;
            F[3] = fv ? R0 : R3;
            #pragma unroll
            for (int i = 0; i < 4; ++i) F[i] = fh ? nrev(F[i]) : F[i];

            if (qd == 0) flg[w*16 + m] = (u32)fv | ((u32)fh << 1);

            // nibbles: row qd (for h) and column qd (for v)
            const u32 Fq = F[qd];
            u32 nbq[4], nbc[4];
            #pragma unroll
            for (int j = 0; j < 4; ++j) nbq[j] = (Fq >> (4*j)) & 15u;
            #pragma unroll
            for (int i = 0; i < 4; ++i) nbc[i] = (F[i] >> (4*qd)) & 15u;

            // 6 packed gathers: each uint2 = all 4 channels (bf16, relu'd)
            uint2 H0 = ThA[nbq[0]*11u + nbq[1]];
            uint2 H1 = ThA[nbq[1]*11u + nbq[2]];
            uint2 H2 = ThA[nbq[2]*11u + nbq[3]];
            uint2 V0 = TvA[nbc[0]*11u + nbc[1]];
            uint2 V1 = TvA[nbc[1]*11u + nbc[2]];
            uint2 V2 = TvA[nbc[2]*11u + nbc[3]];

            u16* zrow = &z1[(w*16 + m) * ZSTR];
            // h position p = qd*3 + j -> k = 4p + c; v position p = i*4 + qd -> k = 48 + 4p + c
            *(uint2*)(zrow + (qd*3 + 0)*4) = H0;
            *(uint2*)(zrow + (qd*3 + 1)*4) = H1;
            *(uint2*)(zrow + (qd*3 + 2)*4) = H2;
            *(uint2*)(zrow + 48 + (0*4 + qd)*4) = V0;
            *(uint2*)(zrow + 48 + (1*4 + qd)*4) = V1;
            *(uint2*)(zrow + 48 + (2*4 + qd)*4) = V2;
        }

        if (it + 1 < ITERS)
            e4 = *(const int4*)(exps + (size_t)(b0 + (it+1)*64 + w*16 + m)*16 + qd*4);

        __syncthreads();  // sync_a: z1/flg ready; previous epilogue reads complete

        fl = flg[qd*16 + m];  // hoisted for NEXT epilogue (stable until next phase1)

        // ---- per board-group G: GEMM1 (bf16 MFMA) -> relu/fp16 in-lane -> GEMM2 (f16 MFMA) ----
        #pragma unroll
        for (int G = 0; G < 4; ++G) {
            bf8 zb[3];
            #pragma unroll
            for (int s = 0; s < 3; ++s)
                zb[s] = *(const bf8*)(&z1[(G*16 + m)*ZSTR + s*32 + qd*8]);

            f4 acc_t[4] = {lb4[0], lb4[1], lb4[2], lb4[3]};
            #pragma unroll
            for (int s = 0; s < 3; ++s)
                #pragma unroll
                for (int tt = 0; tt < 4; ++tt)
                    acc_t[tt] = __builtin_amdgcn_mfma_f32_16x16x32_bf16(af[tt][s], zb[s], acc_t[tt], 0, 0, 0);

            // M-permutation makes lane (qd,m)'s acc rows = features 32c+8qd+j of board m:
            // B-frag for GEMM2 chunk c is relu+pack of acc_t[2c],acc_t[2c+1] -- in-lane.
            f4 acc2 = {0.f, 0.f, 0.f, 0.f};
            #pragma unroll
            for (int c = 0; c < 2; ++c) {
                union { u32 u[4]; h8 v; } bu, au;
                bu.u[0] = pkh(fmaxf(acc_t[2*c  ][0], 0.f), fmaxf(acc_t[2*c  ][1], 0.f));
                bu.u[1] = pkh(fmaxf(acc_t[2*c  ][2], 0.f), fmaxf(acc_t[2*c  ][3], 0.f));
                bu.u[2] = pkh(fmaxf(acc_t[2*c+1][0], 0.f), fmaxf(acc_t[2*c+1][1], 0.f));
                bu.u[3] = pkh(fmaxf(acc_t[2*c+1][2], 0.f), fmaxf(acc_t[2*c+1][3], 0.f));
                au.u[0] = owA[c][0]; au.u[1] = owA[c][1]; au.u[2] = owA[c][2]; au.u[3] = owA[c][3];
                acc2 = __builtin_amdgcn_mfma_f32_16x16x32_f16(au.v, bu.v, acc2, 0, 0, 0);
            }
            // D rows 0-3 (= actions) live in qd==0 lanes, col = board m
            if (qd == 0)
                Pbuf[G][w][m] = make_float4(acc2[0], acc2[1], acc2[2], acc2[3]);
        }
        __syncthreads();  // sync_b: Pbuf complete; z1 safe to overwrite next iter
    }

    // ---- final epilogue (it = ITERS-1) ----
    {
        float4 s0 = Pbuf[qd][0][m], s1 = Pbuf[qd][1][m];
        float4 s2 = Pbuf[qd][2][m], s3 = Pbuf[qd][3][m];
        float L0 = s0.x + s1.x + s2.x + s3.x + obv.x;
        float L1 = s0.y + s1.y + s2.y + s3.y + obv.y;
        float L2 = s0.z + s1.z + s2.z + s3.z + obv.z;
        float L3 = s0.w + s1.w + s2.w + s3.w + obv.w;
        float mx = fmaxf(fmaxf(L0, L1), fmaxf(L2, L3));
        float e0 = __expf(L0 - mx), e1 = __expf(L1 - mx), e2 = __expf(L2 - mx), e3 = __expf(L3 - mx);
        float inv = 1.0f / (e0 + e1 + e2 + e3);
        float p0 = e0 * inv, p1 = e1 * inv, p2 = e2 * inv, p3 = e3 * inv;
        float4 o;
        o.x = (fl & 1u) ? p1 : p0;
        o.y = (fl & 1u) ? p0 : p1;
        o.z = (fl & 2u) ? p3 : p2;
        o.w = (fl & 2u) ? p2 : p3;
        *(float4*)(out + (size_t)(b0 + (ITERS-1)*64 + qd*16 + m) * 4) = o;
    }
}

extern "C" void kernel_launch(void* const* d_in, const int* in_sizes, int n_in,
                              void* d_out, int out_size, void* d_ws, size_t ws_size,
                              hipStream_t stream) {
    const int*   exps = (const int*)  d_in[0];
    const float* c0w  = (const float*)d_in[1];
    const float* c0b  = (const float*)d_in[2];
    const float* c1w  = (const float*)d_in[3];
    const float* lw   = (const float*)d_in[4];
    const float* lbv  = (const float*)d_in[5];
    const float* oww  = (const float*)d_in[6];
    const float* obv  = (const float*)d_in[7];
    smartcnn_fused<<<NBLK, 256, 0, stream>>>(exps, c0w, c0b, c1w, lw, lbv, oww, obv, (float*)d_out);
}

// Round 13
// 102.138 us; speedup vs baseline: 1.1383x; 1.1383x over previous
//
#include <hip/hip_runtime.h>

typedef unsigned int  u32;
typedef unsigned short u16;

typedef float    f4  __attribute__((ext_vector_type(4)));
typedef short    bf8 __attribute__((ext_vector_type(8)));
typedef __fp16   h8  __attribute__((ext_vector_type(8)));
typedef __fp16   h2  __attribute__((ext_vector_type(2)));

#define NBLK  1024
#define ITERS 4      // must be even; 1024 * 4 * 64 = 262144 boards
#define ZSTR  104    // z1 row stride (u16); 52 dw/row spreads b128 starts over all 8 bank slots

// round-to-nearest-even fp32 -> bf16 bits
__device__ __forceinline__ u32 bfr(float f) {
    union { float f; u32 u; } v; v.f = f;
    return (v.u + 0x7fffu + ((v.u >> 16) & 1u)) >> 16;
}
__device__ __forceinline__ u32 pk2(float lo, float hi) { return bfr(lo) | (bfr(hi) << 16); }
__device__ __forceinline__ u32 pkh(float lo, float hi) {   // fp16 pair (RTZ, 1 inst)
    union { h2 h; u32 u; } v; v.h = __builtin_amdgcn_cvt_pkrtz(lo, hi); return v.u;
}
__device__ __forceinline__ u32 nrev(u32 x) {
    return ((x >> 12) & 0xFu) | ((x >> 4) & 0xF0u) | ((x << 4) & 0xF00u) | ((x << 12) & 0xF000u);
}

// ---- phase 1: build z1 rows + flip flags for this wave's 16 boards ----
__device__ __forceinline__ void phase1_fn(const int4 e4, u16* __restrict__ z1b, u32* __restrict__ flgb,
                                          const uint2* __restrict__ Th, const uint2* __restrict__ Tv,
                                          const int w, const int m, const int qd)
{
    u32 pkd = (u32)e4.x | ((u32)e4.y << 4) | ((u32)e4.z << 8) | ((u32)e4.w << 12);
    u32 R0 = (u32)__shfl((int)pkd, m);
    u32 R1 = (u32)__shfl((int)pkd, m + 16);
    u32 R2 = (u32)__shfl((int)pkd, m + 32);
    u32 R3 = (u32)__shfl((int)pkd, m + 48);
    u32 c0v = R0 & 15u, c1v = (R0 >> 12) & 15u, c2v = R3 & 15u, c3v = (R3 >> 12) & 15u;
    u32 best = c0v; int ix = 0;
    if (c1v > best) { best = c1v; ix = 1; }
    if (c2v > best) { best = c2v; ix = 2; }
    if (c3v > best) { best = c3v; ix = 3; }
    const bool fv = (ix >= 2), fh = ((ix & 1) != 0);
    u32 F[4];
    F[0] = fv ? R3 : R0;
    F[1] = fv ? R2 : R1;
    F[2] = fv ? R1 : R2;
    F[3] = fv ? R0 : R3;
    #pragma unroll
    for (int i = 0; i < 4; ++i) F[i] = fh ? nrev(F[i]) : F[i];

    if (qd == 0) flgb[w*16 + m] = (u32)fv | ((u32)fh << 1);

    const u32 Fq = F[qd];
    u32 nbq[4], nbc[4];
    #pragma unroll
    for (int j = 0; j < 4; ++j) nbq[j] = (Fq >> (4*j)) & 15u;
    #pragma unroll
    for (int i = 0; i < 4; ++i) nbc[i] = (F[i] >> (4*qd)) & 15u;

    uint2 H0 = Th[nbq[0]*11u + nbq[1]];
    uint2 H1 = Th[nbq[1]*11u + nbq[2]];
    uint2 H2 = Th[nbq[2]*11u + nbq[3]];
    uint2 V0 = Tv[nbc[0]*11u + nbc[1]];
    uint2 V1 = Tv[nbc[1]*11u + nbc[2]];
    uint2 V2 = Tv[nbc[2]*11u + nbc[3]];

    u16* zrow = &z1b[(w*16 + m) * ZSTR];
    *(uint2*)(zrow + (qd*3 + 0)*4) = H0;
    *(uint2*)(zrow + (qd*3 + 1)*4) = H1;
    *(uint2*)(zrow + (qd*3 + 2)*4) = H2;
    *(uint2*)(zrow + 48 + (0*4 + qd)*4) = V0;
    *(uint2*)(zrow + 48 + (1*4 + qd)*4) = V1;
    *(uint2*)(zrow + 48 + (2*4 + qd)*4) = V2;
}

// ---- GEMM1 (bf16 MFMA) -> relu/fp16 in-lane -> GEMM2 (f16 MFMA) -> Pbuf partials ----
__device__ __forceinline__ void gemm_fn(const u16* __restrict__ z1b, float4* __restrict__ Pb,
                                        const bf8 (&af)[4][3], const u32 (&owA)[2][4], const f4 (&lb4)[4],
                                        const int w, const int m, const int qd)
{
    #pragma unroll
    for (int G = 0; G < 4; ++G) {
        bf8 zb[3];
        #pragma unroll
        for (int s = 0; s < 3; ++s)
            zb[s] = *(const bf8*)(&z1b[(G*16 + m)*ZSTR + s*32 + qd*8]);

        f4 acc_t[4] = {lb4[0], lb4[1], lb4[2], lb4[3]};
        #pragma unroll
        for (int s = 0; s < 3; ++s)
            #pragma unroll
            for (int tt = 0; tt < 4; ++tt)
                acc_t[tt] = __builtin_amdgcn_mfma_f32_16x16x32_bf16(af[tt][s], zb[s], acc_t[tt], 0, 0, 0);

        // M-permutation: lane (qd,m)'s acc rows = features 32c+8qd+j of board m -> in-lane B-frag
        f4 acc2 = {0.f, 0.f, 0.f, 0.f};
        #pragma unroll
        for (int c = 0; c < 2; ++c) {
            union { u32 u[4]; h8 v; } bu, au;
            bu.u[0] = pkh(fmaxf(acc_t[2*c  ][0], 0.f), fmaxf(acc_t[2*c  ][1], 0.f));
            bu.u[1] = pkh(fmaxf(acc_t[2*c  ][2], 0.f), fmaxf(acc_t[2*c  ][3], 0.f));
            bu.u[2] = pkh(fmaxf(acc_t[2*c+1][0], 0.f), fmaxf(acc_t[2*c+1][1], 0.f));
            bu.u[3] = pkh(fmaxf(acc_t[2*c+1][2], 0.f), fmaxf(acc_t[2*c+1][3], 0.f));
            au.u[0] = owA[c][0]; au.u[1] = owA[c][1]; au.u[2] = owA[c][2]; au.u[3] = owA[c][3];
            acc2 = __builtin_amdgcn_mfma_f32_16x16x32_f16(au.v, bu.v, acc2, 0, 0, 0);
        }
        if (qd == 0)
            Pb[(G*4 + w)*16 + m] = make_float4(acc2[0], acc2[1], acc2[2], acc2[3]);
    }
}

// ---- epilogue: softmax + flip-permute + store for board base + qd*16 + m ----
__device__ __forceinline__ void epi_fn(const float4* __restrict__ Pb, const u32 fl, const float4 obv,
                                       float* __restrict__ out, const int base, const int m, const int qd)
{
    float4 s0 = Pb[(qd*4 + 0)*16 + m], s1 = Pb[(qd*4 + 1)*16 + m];
    float4 s2 = Pb[(qd*4 + 2)*16 + m], s3 = Pb[(qd*4 + 3)*16 + m];
    float L0 = s0.x + s1.x + s2.x + s3.x + obv.x;
    float L1 = s0.y + s1.y + s2.y + s3.y + obv.y;
    float L2 = s0.z + s1.z + s2.z + s3.z + obv.z;
    float L3 = s0.w + s1.w + s2.w + s3.w + obv.w;
    float mx = fmaxf(fmaxf(L0, L1), fmaxf(L2, L3));
    float e0 = __expf(L0 - mx), e1 = __expf(L1 - mx), e2 = __expf(L2 - mx), e3 = __expf(L3 - mx);
    float inv = 1.0f / (e0 + e1 + e2 + e3);
    float p0 = e0 * inv, p1 = e1 * inv, p2 = e2 * inv, p3 = e3 * inv;
    float4 o;
    o.x = (fl & 1u) ? p1 : p0;
    o.y = (fl & 1u) ? p0 : p1;
    o.z = (fl & 2u) ? p3 : p2;
    o.w = (fl & 2u) ? p2 : p3;
    *(float4*)(out + (size_t)(base + qd*16 + m) * 4) = o;
}

__launch_bounds__(256, 4)
__global__ void smartcnn_fused(const int* __restrict__ exps,
                               const float* __restrict__ c0w, const float* __restrict__ c0b,
                               const float* __restrict__ c1w,
                               const float* __restrict__ lw,  const float* __restrict__ lb,
                               const float* __restrict__ ow,  const float* __restrict__ ob,
                               float* __restrict__ out)
{
    __shared__ uint2  ThA[121];          // [v1*11+v2] -> 4 channels bf16 (relu(conv0 pair + bias))
    __shared__ uint2  TvA[121];          // [v1*11+v2] -> 4 channels bf16 (relu(conv1 pair))
    __shared__ u16    z1A[64 * ZSTR];    // double-buffered z1 (STATIC names -> no dynamic indexing)
    __shared__ u16    z1B[64 * ZSTR];
    __shared__ float4 PbA[4*4*16];       // double-buffered logit partials [(G*4+w)*16+m]
    __shared__ float4 PbB[4*4*16];
    __shared__ u32    flgA[64];          // double-buffered flip flags
    __shared__ u32    flgB[64];

    const int tid  = threadIdx.x;
    const int w    = tid >> 6;
    const int lane = tid & 63;
    const int m    = lane & 15;
    const int qd   = lane >> 4;

    // ---- packed-channel pair tables ----
    for (int i = tid; i < 121; i += 256) {
        int v1 = i / 11, v2 = i - v1 * 11;
        float hv[4], vv[4];
        #pragma unroll
        for (int c = 0; c < 4; ++c) {
            hv[c] = fmaxf(c0w[c*24 + 0] + c0w[c*24 + (1+v1)*2 + 0] + c0b[c]
                        + c0w[c*24 + 1] + c0w[c*24 + (1+v2)*2 + 1], 0.f);
            vv[c] = fmaxf(c1w[c*24 + 0] + c1w[c*24 + (1+v1)*2 + 0]
                        + c1w[c*24 + 1] + c1w[c*24 + (1+v2)*2 + 1], 0.f);
        }
        ThA[i] = make_uint2(pk2(hv[0], hv[1]), pk2(hv[2], hv[3]));
        TvA[i] = make_uint2(pk2(vv[0], vv[1]), pk2(vv[2], vv[3]));
    }

    // ---- W1 A-fragments (48 VGPR), K-permuted + M-permuted, staged through z1A ----
    // FULLY UNROLLED over tt (R8 post-mortem: dynamic af indexing demotes to scratch).
    // Wave w uses only its own z1A rows; same-wave DS ordering makes later reuse WAR-safe.
    bf8 af[4][3];
    {
        u16* srow = &z1A[(w*16 + m) * ZSTR];
        #pragma unroll
        for (int tt = 0; tt < 4; ++tt) {
            const int tbase = ((tt & 1) ? 4 : 0) + ((tt >> 1) ? 32 : 0);
            const int fid = 64*w + tbase + 8*(m >> 2) + (m & 3);   // M-permuted feature row
            const float* rowp = lw + (size_t)fid*96 + qd*24;
            #pragma unroll
            for (int v = 0; v < 6; ++v) {
                float4 x = *(const float4*)(rowp + v*4);
                u16 e[4] = {(u16)bfr(x.x), (u16)bfr(x.y), (u16)bfr(x.z), (u16)bfr(x.w)};
                #pragma unroll
                for (int j = 0; j < 4; ++j) {
                    int ko = qd*24 + v*4 + j;
                    int kp = (ko < 48) ? ((ko % 12)*4 + ko/12)
                                       : (48 + ((ko - 48) % 12)*4 + (ko - 48)/12);
                    srow[kp] = e[j];
                }
            }
            #pragma unroll
            for (int s = 0; s < 3; ++s)
                af[tt][s] = *(const bf8*)(srow + s*32 + qd*8);
        }
    }
    // ---- out_w A-fragments, fp16 (8 VGPR): rows 0-3 = actions, rows 4-15 = 0 ----
    u32 owA[2][4];
    #pragma unroll
    for (int c = 0; c < 2; ++c) {
        int n8 = 64*w + 32*c + qd*8;
        #pragma unroll
        for (int k = 0; k < 4; ++k)
            owA[c][k] = (m < 4) ? pkh(ow[m*256 + n8 + 2*k], ow[m*256 + n8 + 2*k + 1]) : 0u;
    }
    // ---- linear_b as f4, M-permuted: lb4[tt][r] = lb[64w + tbase(tt) + 8qd + r] ----
    f4 lb4[4];
    #pragma unroll
    for (int tt = 0; tt < 4; ++tt) {
        const int tbase = ((tt & 1) ? 4 : 0) + ((tt >> 1) ? 32 : 0);
        lb4[tt] = *(const f4*)(lb + 64*w + tbase + 8*qd);
    }
    const float4 obv = *(const float4*)ob;

    const int b0 = blockIdx.x * (ITERS * 64);
    __syncthreads();  // tables published (z1A staging is same-wave, needs no barrier)

    // ---- pre-loop: fill A buffers for it=0 ----
    int4 e4 = *(const int4*)(exps + (size_t)(b0 + w*16 + m)*16 + qd*4);
    phase1_fn(e4, z1A, flgA, &ThA[0], &TvA[0], w, m, qd);
    e4 = *(const int4*)(exps + (size_t)(b0 + 64 + w*16 + m)*16 + qd*4);
    __syncthreads();  // z1A/flgA (it=0) published

    // ---- pipelined pair loop: 1 barrier per iteration, work on both sides ----
    #pragma unroll 1
    for (int itp = 0; itp < ITERS/2; ++itp) {
        const int it = itp * 2;

        const u32 flA = flgA[qd*16 + m];              // it data (published)
        phase1_fn(e4, z1B, flgB, &ThA[0], &TvA[0], w, m, qd);   // it+1 -> B
        if (it + 2 < ITERS)
            e4 = *(const int4*)(exps + (size_t)(b0 + (it+2)*64 + w*16 + m)*16 + qd*4);
        gemm_fn(z1A, PbA, af, owA, lb4, w, m, qd);    // it

        __syncthreads();  // b1: PbA + z1B/flgB published; all z1A readers retired

        epi_fn(PbA, flA, obv, out, b0 + it*64, m, qd);
        const u32 flB = flgB[qd*16 + m];              // it+1 data (published at b1)
        if (it + 2 < ITERS) {
            phase1_fn(e4, z1A, flgA, &ThA[0], &TvA[0], w, m, qd);   // it+2 -> A
            if (it + 3 < ITERS)
                e4 = *(const int4*)(exps + (size_t)(b0 + (it+3)*64 + w*16 + m)*16 + qd*4);
        }
        gemm_fn(z1B, PbB, af, owA, lb4, w, m, qd);    // it+1

        __syncthreads();  // b2: PbB + z1A/flgA(it+2) published; all z1B readers retired

        epi_fn(PbB, flB, obv, out, b0 + (it+1)*64, m, qd);
        // next pair's phase1(it+3)->B only touches z1B/flgB, whose readers retired at b2
    }
}

extern "C" void kernel_launch(void* const* d_in, const int* in_sizes, int n_in,
                              void* d_out, int out_size, void* d_ws, size_t ws_size,
                              hipStream_t stream) {
    const int*   exps = (const int*)  d_in[0];
    const float* c0w  = (const float*)d_in[1];
    const float* c0b  = (const float*)d_in[2];
    const float* c1w  = (const float*)d_in[3];
    const float* lw   = (const float*)d_in[4];
    const float* lbv  = (const float*)d_in[5];
    const float* oww  = (const float*)d_in[6];
    const float* obv  = (const float*)d_in[7];
    smartcnn_fused<<<NBLK, 256, 0, stream>>>(exps, c0w, c0b, c1w, lw, lbv, oww, obv, (float*)d_out);
}

// Round 14
// 102.038 us; speedup vs baseline: 1.1394x; 1.0010x over previous
//
#include <hip/hip_runtime.h>

typedef unsigned int  u32;
typedef unsigned short u16;

typedef float    f4  __attribute__((ext_vector_type(4)));
typedef short    bf8 __attribute__((ext_vector_type(8)));
typedef __fp16   h8  __attribute__((ext_vector_type(8)));
typedef __fp16   h2  __attribute__((ext_vector_type(2)));

#define NBLK  1024
#define ITERS 4      // must be even; 1024 * 4 * 64 = 262144 boards
#define ZSTR  104    // z1 row stride (u16); 52 dw/row -> b128 starts on 8 disjoint 4-bank groups

// fp32 -> bf16 bits, round-half-up (setup only; 2 VALU vs 4 for RNE, ties are measure-zero)
__device__ __forceinline__ u32 bfr(float f) {
    union { float f; u32 u; } v; v.f = f;
    return (v.u + 0x8000u) >> 16;
}
__device__ __forceinline__ u32 pk2(float lo, float hi) { return bfr(lo) | (bfr(hi) << 16); }
__device__ __forceinline__ u32 pkh(float lo, float hi) {   // fp16 pair (RTZ, 1 inst)
    union { h2 h; u32 u; } v; v.h = __builtin_amdgcn_cvt_pkrtz(lo, hi); return v.u;
}
__device__ __forceinline__ u32 nrev(u32 x) {
    return ((x >> 12) & 0xFu) | ((x >> 4) & 0xF0u) | ((x << 4) & 0xF00u) | ((x << 12) & 0xF000u);
}

// ---- phase 1: build z1 rows + flip flags for this wave's 16 boards ----
__device__ __forceinline__ void phase1_fn(const int4 e4, u16* __restrict__ z1b, u32* __restrict__ flgb,
                                          const uint2* __restrict__ Th, const uint2* __restrict__ Tv,
                                          const int w, const int m, const int qd)
{
    u32 pkd = (u32)e4.x | ((u32)e4.y << 4) | ((u32)e4.z << 8) | ((u32)e4.w << 12);
    u32 R0 = (u32)__shfl((int)pkd, m);
    u32 R1 = (u32)__shfl((int)pkd, m + 16);
    u32 R2 = (u32)__shfl((int)pkd, m + 32);
    u32 R3 = (u32)__shfl((int)pkd, m + 48);
    u32 c0v = R0 & 15u, c1v = (R0 >> 12) & 15u, c2v = R3 & 15u, c3v = (R3 >> 12) & 15u;
    u32 best = c0v; int ix = 0;
    if (c1v > best) { best = c1v; ix = 1; }
    if (c2v > best) { best = c2v; ix = 2; }
    if (c3v > best) { best = c3v; ix = 3; }
    const bool fv = (ix >= 2), fh = ((ix & 1) != 0);
    u32 F[4];
    F[0] = fv ? R3 : R0;
    F[1] = fv ? R2 : R1;
    F[2] = fv ? R1 : R2;
    F[3] = fv ? R0 : R3;
    #pragma unroll
    for (int i = 0; i < 4; ++i) F[i] = fh ? nrev(F[i]) : F[i];

    if (qd == 0) flgb[w*16 + m] = (u32)fv | ((u32)fh << 1);

    const u32 Fq = F[qd];
    u32 nbq[4], nbc[4];
    #pragma unroll
    for (int j = 0; j < 4; ++j) nbq[j] = (Fq >> (4*j)) & 15u;
    #pragma unroll
    for (int i = 0; i < 4; ++i) nbc[i] = (F[i] >> (4*qd)) & 15u;

    uint2 H0 = Th[nbq[0]*11u + nbq[1]];
    uint2 H1 = Th[nbq[1]*11u + nbq[2]];
    uint2 H2 = Th[nbq[2]*11u + nbq[3]];
    uint2 V0 = Tv[nbc[0]*11u + nbc[1]];
    uint2 V1 = Tv[nbc[1]*11u + nbc[2]];
    uint2 V2 = Tv[nbc[2]*11u + nbc[3]];

    u16* zrow = &z1b[(w*16 + m) * ZSTR];
    *(uint2*)(zrow + (qd*3 + 0)*4) = H0;
    *(uint2*)(zrow + (qd*3 + 1)*4) = H1;
    *(uint2*)(zrow + (qd*3 + 2)*4) = H2;
    *(uint2*)(zrow + 48 + (0*4 + qd)*4) = V0;
    *(uint2*)(zrow + 48 + (1*4 + qd)*4) = V1;
    *(uint2*)(zrow + 48 + (2*4 + qd)*4) = V2;
}

// ---- GEMM1 (bf16 MFMA) -> relu/fp16 in-lane -> GEMM2 (f16 MFMA) -> Pbuf partials ----
__device__ __forceinline__ void gemm_fn(const u16* __restrict__ z1b, float4* __restrict__ Pb,
                                        const bf8 (&af)[4][3], const u32 (&owA)[2][4], const f4 (&lb4)[4],
                                        const int w, const int m, const int qd)
{
    #pragma unroll
    for (int G = 0; G < 4; ++G) {
        bf8 zb[3];
        #pragma unroll
        for (int s = 0; s < 3; ++s)
            zb[s] = *(const bf8*)(&z1b[(G*16 + m)*ZSTR + s*32 + qd*8]);

        f4 acc_t[4] = {lb4[0], lb4[1], lb4[2], lb4[3]};
        #pragma unroll
        for (int s = 0; s < 3; ++s)
            #pragma unroll
            for (int tt = 0; tt < 4; ++tt)
                acc_t[tt] = __builtin_amdgcn_mfma_f32_16x16x32_bf16(af[tt][s], zb[s], acc_t[tt], 0, 0, 0);

        // M-permutation: lane (qd,m)'s acc rows = features 32c+8qd+j of board m -> in-lane B-frag
        f4 acc2 = {0.f, 0.f, 0.f, 0.f};
        #pragma unroll
        for (int c = 0; c < 2; ++c) {
            union { u32 u[4]; h8 v; } bu, au;
            bu.u[0] = pkh(fmaxf(acc_t[2*c  ][0], 0.f), fmaxf(acc_t[2*c  ][1], 0.f));
            bu.u[1] = pkh(fmaxf(acc_t[2*c  ][2], 0.f), fmaxf(acc_t[2*c  ][3], 0.f));
            bu.u[2] = pkh(fmaxf(acc_t[2*c+1][0], 0.f), fmaxf(acc_t[2*c+1][1], 0.f));
            bu.u[3] = pkh(fmaxf(acc_t[2*c+1][2], 0.f), fmaxf(acc_t[2*c+1][3], 0.f));
            au.u[0] = owA[c][0]; au.u[1] = owA[c][1]; au.u[2] = owA[c][2]; au.u[3] = owA[c][3];
            acc2 = __builtin_amdgcn_mfma_f32_16x16x32_f16(au.v, bu.v, acc2, 0, 0, 0);
        }
        if (qd == 0)
            Pb[(G*4 + w)*16 + m] = make_float4(acc2[0], acc2[1], acc2[2], acc2[3]);
    }
}

// ---- epilogue: softmax + flip-permute + store for board base + qd*16 + m ----
__device__ __forceinline__ void epi_fn(const float4* __restrict__ Pb, const u32 fl, const float4 obv,
                                       float* __restrict__ out, const int base, const int m, const int qd)
{
    float4 s0 = Pb[(qd*4 + 0)*16 + m], s1 = Pb[(qd*4 + 1)*16 + m];
    float4 s2 = Pb[(qd*4 + 2)*16 + m], s3 = Pb[(qd*4 + 3)*16 + m];
    float L0 = s0.x + s1.x + s2.x + s3.x + obv.x;
    float L1 = s0.y + s1.y + s2.y + s3.y + obv.y;
    float L2 = s0.z + s1.z + s2.z + s3.z + obv.z;
    float L3 = s0.w + s1.w + s2.w + s3.w + obv.w;
    float mx = fmaxf(fmaxf(L0, L1), fmaxf(L2, L3));
    float e0 = __expf(L0 - mx), e1 = __expf(L1 - mx), e2 = __expf(L2 - mx), e3 = __expf(L3 - mx);
    float inv = __builtin_amdgcn_rcpf(e0 + e1 + e2 + e3);   // ~1 ulp; prob err ~1e-7
    float p0 = e0 * inv, p1 = e1 * inv, p2 = e2 * inv, p3 = e3 * inv;
    float4 o;
    o.x = (fl & 1u) ? p1 : p0;
    o.y = (fl & 1u) ? p0 : p1;
    o.z = (fl & 2u) ? p3 : p2;
    o.w = (fl & 2u) ? p2 : p3;
    *(float4*)(out + (size_t)(base + qd*16 + m) * 4) = o;
}

__launch_bounds__(256, 4)
__global__ void smartcnn_fused(const int* __restrict__ exps,
                               const float* __restrict__ c0w, const float* __restrict__ c0b,
                               const float* __restrict__ c1w,
                               const float* __restrict__ lw,  const float* __restrict__ lb,
                               const float* __restrict__ ow,  const float* __restrict__ ob,
                               float* __restrict__ out)
{
    __shared__ uint2  ThA[121];          // [v1*11+v2] -> 4 channels bf16 (relu(conv0 pair + bias))
    __shared__ uint2  TvA[121];          // [v1*11+v2] -> 4 channels bf16 (relu(conv1 pair))
    __shared__ u16    z1A[64 * ZSTR];    // double-buffered z1 (STATIC names -> no dynamic indexing)
    __shared__ u16    z1B[64 * ZSTR];
    __shared__ float4 PbA[4*4*16];       // double-buffered logit partials [(G*4+w)*16+m]
    __shared__ float4 PbB[4*4*16];
    __shared__ u32    flgA[64];          // double-buffered flip flags
    __shared__ u32    flgB[64];

    const int tid  = threadIdx.x;
    const int w    = tid >> 6;
    const int lane = tid & 63;
    const int m    = lane & 15;
    const int qd   = lane >> 4;

    // ---- packed-channel pair tables ----
    for (int i = tid; i < 121; i += 256) {
        int v1 = i / 11, v2 = i - v1 * 11;
        float hv[4], vv[4];
        #pragma unroll
        for (int c = 0; c < 4; ++c) {
            hv[c] = fmaxf(c0w[c*24 + 0] + c0w[c*24 + (1+v1)*2 + 0] + c0b[c]
                        + c0w[c*24 + 1] + c0w[c*24 + (1+v2)*2 + 1], 0.f);
            vv[c] = fmaxf(c1w[c*24 + 0] + c1w[c*24 + (1+v1)*2 + 0]
                        + c1w[c*24 + 1] + c1w[c*24 + (1+v2)*2 + 1], 0.f);
        }
        ThA[i] = make_uint2(pk2(hv[0], hv[1]), pk2(hv[2], hv[3]));
        TvA[i] = make_uint2(pk2(vv[0], vv[1]), pk2(vv[2], vv[3]));
    }

    // ---- W1 A-fragments (48 VGPR), K-permuted + M-permuted, staged through z1A ----
    // FULLY UNROLLED over tt (R8 post-mortem: dynamic af indexing demotes to scratch).
    // Wave w uses only its own z1A rows; same-wave DS ordering makes later reuse WAR-safe.
    bf8 af[4][3];
    {
        u16* srow = &z1A[(w*16 + m) * ZSTR];
        #pragma unroll
        for (int tt = 0; tt < 4; ++tt) {
            const int tbase = ((tt & 1) ? 4 : 0) + ((tt >> 1) ? 32 : 0);
            const int fid = 64*w + tbase + 8*(m >> 2) + (m & 3);   // M-permuted feature row
            const float* rowp = lw + (size_t)fid*96 + qd*24;
            #pragma unroll
            for (int v = 0; v < 6; ++v) {
                float4 x = *(const float4*)(rowp + v*4);
                u16 e[4] = {(u16)bfr(x.x), (u16)bfr(x.y), (u16)bfr(x.z), (u16)bfr(x.w)};
                #pragma unroll
                for (int j = 0; j < 4; ++j) {
                    int ko = qd*24 + v*4 + j;
                    int kp = (ko < 48) ? ((ko % 12)*4 + ko/12)
                                       : (48 + ((ko - 48) % 12)*4 + (ko - 48)/12);
                    srow[kp] = e[j];
                }
            }
            #pragma unroll
            for (int s = 0; s < 3; ++s)
                af[tt][s] = *(const bf8*)(srow + s*32 + qd*8);
        }
    }
    // ---- out_w A-fragments, fp16 (8 VGPR): rows 0-3 = actions, rows 4-15 = 0 ----
    u32 owA[2][4];
    #pragma unroll
    for (int c = 0; c < 2; ++c) {
        int n8 = 64*w + 32*c + qd*8;
        #pragma unroll
        for (int k = 0; k < 4; ++k)
            owA[c][k] = (m < 4) ? pkh(ow[m*256 + n8 + 2*k], ow[m*256 + n8 + 2*k + 1]) : 0u;
    }
    // ---- linear_b as f4, M-permuted: lb4[tt][r] = lb[64w + tbase(tt) + 8qd + r] ----
    f4 lb4[4];
    #pragma unroll
    for (int tt = 0; tt < 4; ++tt) {
        const int tbase = ((tt & 1) ? 4 : 0) + ((tt >> 1) ? 32 : 0);
        lb4[tt] = *(const f4*)(lb + 64*w + tbase + 8*qd);
    }
    const float4 obv = *(const float4*)ob;

    const int b0 = blockIdx.x * (ITERS * 64);
    __syncthreads();  // tables published (z1A staging is same-wave, needs no barrier)

    // ---- pre-loop: fill A buffers for it=0 ----
    int4 e4 = *(const int4*)(exps + (size_t)(b0 + w*16 + m)*16 + qd*4);
    phase1_fn(e4, z1A, flgA, &ThA[0], &TvA[0], w, m, qd);
    e4 = *(const int4*)(exps + (size_t)(b0 + 64 + w*16 + m)*16 + qd*4);
    __syncthreads();  // z1A/flgA (it=0) published

    // ---- pipelined pair loop: 1 barrier per iteration, work on both sides ----
    // (fully unrolled: ITERS/2 = 2 pairs, static buffer names keep af/regs statically indexed)
    #pragma unroll
    for (int itp = 0; itp < ITERS/2; ++itp) {
        const int it = itp * 2;

        const u32 flA = flgA[qd*16 + m];              // it data (published)
        phase1_fn(e4, z1B, flgB, &ThA[0], &TvA[0], w, m, qd);   // it+1 -> B
        if (it + 2 < ITERS)
            e4 = *(const int4*)(exps + (size_t)(b0 + (it+2)*64 + w*16 + m)*16 + qd*4);
        gemm_fn(z1A, PbA, af, owA, lb4, w, m, qd);    // it

        __syncthreads();  // b1: PbA + z1B/flgB published; all z1A readers retired

        const u32 flB = flgB[qd*16 + m];              // it+1 data (published at b1)
        if (it + 2 < ITERS) {
            phase1_fn(e4, z1A, flgA, &ThA[0], &TvA[0], w, m, qd);   // it+2 -> A (gathers issue early)
            if (it + 3 < ITERS)
                e4 = *(const int4*)(exps + (size_t)(b0 + (it+3)*64 + w*16 + m)*16 + qd*4);
        }
        epi_fn(PbA, flA, obv, out, b0 + it*64, m, qd);   // epi VALU hides phase1 gather latency
        gemm_fn(z1B, PbB, af, owA, lb4, w, m, qd);    // it+1

        __syncthreads();  // b2: PbB + z1A/flgA(it+2) published; all z1B readers retired

        epi_fn(PbB, flB, obv, out, b0 + (it+1)*64, m, qd);
        // next pair's phase1(it+3)->B only touches z1B/flgB, whose readers retired at b2
    }
}

extern "C" void kernel_launch(void* const* d_in, const int* in_sizes, int n_in,
                              void* d_out, int out_size, void* d_ws, size_t ws_size,
                              hipStream_t stream) {
    const int*   exps = (const int*)  d_in[0];
    const float* c0w  = (const float*)d_in[1];
    const float* c0b  = (const float*)d_in[2];
    const float* c1w  = (const float*)d_in[3];
    const float* lw   = (const float*)d_in[4];
    const float* lbv  = (const float*)d_in[5];
    const float* oww  = (const float*)d_in[6];
    const float* obv  = (const float*)d_in[7];
    smartcnn_fused<<<NBLK, 256, 0, stream>>>(exps, c0w, c0b, c1w, lw, lbv, oww, obv, (float*)d_out);
}